// Round 7
// baseline (202.482 us; speedup 1.0000x reference)
//
#include <hip/hip_runtime.h>
#include <math.h>

typedef unsigned short u16;
typedef unsigned int   u32;

typedef __attribute__((ext_vector_type(8))) short short8;
typedef __attribute__((ext_vector_type(4))) float f32x4;

static constexpr int CB  = 4;
static constexpr int CNP = 32768;
static constexpr int CM  = 64;
static constexpr int CDO = 13;
static constexpr int CH  = 256;
static constexpr int DXP_ELEMS = CB * CNP * CDO;   // 1703936 floats; dx_o follows

// ws layout: [0,16384) bytes = mobj float[4096]; frag pool (bf16) at byte 16384.
static constexpr int WSB_FRAG = 16384;
// frag pool offsets (bf16 elems) — all multiples of 256
static constexpr int F_EW0 = 0;        // 8192   (31x256 -> K32)
static constexpr int F_EW1 = 8192;     // 65536  (256x256)
static constexpr int F_EW2 = 73728;    // 4096   (256x13 -> N16)
static constexpr int F_VW0 = 77824;    // 8192   (27x256 -> K32)
static constexpr int F_VW1 = 86016;    // 65536
static constexpr int F_VW2 = 151552;   // 65536
static constexpr int F_VW3 = 217088;   // 4096   (256x3 -> N16)
static constexpr int F_OW0 = 221184;
static constexpr int F_OW1 = 229376;
static constexpr int F_OW2 = 294912;
static constexpr int F_OW3 = 360448;
static constexpr int F_TOTAL = 364544;

__device__ __forceinline__ float bf2f(u16 v) { return __uint_as_float(((u32)v) << 16); }
__device__ __forceinline__ u16 f2bf(float f) {
    u32 u = __float_as_uint(f);
    u += 0x7fffu + ((u >> 16) & 1u);
    return (u16)(u >> 16);
}
// fast tanh-gelu (max |err| vs exact erf-gelu ~1.5e-3, well inside 2% budget)
__device__ __forceinline__ float gelu_f(float x) {
    float y = 0.7978845608028654f * (x + 0.044715f * x * x * x);
    float e = __expf(2.0f * y);
    float t = 1.0f - 2.0f / (e + 1.0f);
    return 0.5f * x * (1.0f + t);
}

struct Segs { const float* src[11]; };

// K0: zero mobj + swizzle ALL MLP weights into MFMA B-fragment order (bf16) in ws.
// Segment boundaries are multiples of 256 => block-uniform scalar branches, no tables.
// B-frag (16x16x32): frag[((kt*NT+nt)*64 + lane)*8 + j] = W[kt*32 + (lane>>4)*8 + j][nt*16 + (lane&15)]
__global__ __launch_bounds__(256) void k0_prep(Segs segs, float* __restrict__ ws,
                                               u16* __restrict__ wsFrag) {
    int idx = blockIdx.x * 256 + threadIdx.x;
    if (idx < 4096) { ws[idx] = 0.0f; return; }
    int f = idx - 4096;
    if (f >= F_TOTAL) return;

    const float* src; int base, K, N, NT;
    if      (f < F_EW1) { src = segs.src[0];  base = F_EW0; K = 31;  N = 256; NT = 16; }
    else if (f < F_EW2) { src = segs.src[1];  base = F_EW1; K = 256; N = 256; NT = 16; }
    else if (f < F_VW0) { src = segs.src[2];  base = F_EW2; K = 256; N = 13;  NT = 1;  }
    else if (f < F_VW1) { src = segs.src[3];  base = F_VW0; K = 27;  N = 256; NT = 16; }
    else if (f < F_VW2) { src = segs.src[4];  base = F_VW1; K = 256; N = 256; NT = 16; }
    else if (f < F_VW3) { src = segs.src[5];  base = F_VW2; K = 256; N = 256; NT = 16; }
    else if (f < F_OW0) { src = segs.src[6];  base = F_VW3; K = 256; N = 3;   NT = 1;  }
    else if (f < F_OW1) { src = segs.src[7];  base = F_OW0; K = 27;  N = 256; NT = 16; }
    else if (f < F_OW2) { src = segs.src[8];  base = F_OW1; K = 256; N = 256; NT = 16; }
    else if (f < F_OW3) { src = segs.src[9];  base = F_OW2; K = 256; N = 256; NT = 16; }
    else                { src = segs.src[10]; base = F_OW3; K = 256; N = 3;   NT = 1;  }

    int rel = f - base;
    int j = rel & 7, lane = (rel >> 3) & 63, t = rel >> 9;
    int nt = (NT == 16) ? (t & 15) : 0;
    int kt = (NT == 16) ? (t >> 4) : t;
    int k = kt * 32 + ((lane >> 4) << 3) + j;
    int n = nt * 16 + (lane & 15);
    float v = (k < K && n < N) ? src[k * N + n] : 0.0f;
    wsFrag[f] = f2bf(v);
}

// K1: fused edge MLP via MFMA. One block per (b,i): all 64 edges j, two passes of 32.
__global__ __launch_bounds__(256) void k1_edge(const float* __restrict__ xo,
                                               const float* __restrict__ tp,
                                               const float* __restrict__ eb0,
                                               const float* __restrict__ eb1,
                                               const float* __restrict__ eb2,
                                               const u16* __restrict__ wsFrag,
                                               float* __restrict__ mobj) {
    __shared__ float sXo[832];
    __shared__ float sAnorm[64];
    __shared__ float sInv;
    __shared__ float sBias[512];           // [0,256)=b0, [256,512)=b1
    __shared__ float sMsg[512];            // 32 edges x 16
    __shared__ __align__(16) u16 sIn[32 * 40];     // 32 edges x K32 (stride 40)
    __shared__ __align__(16) u16 sH1[32 * 264];    // 32 edges x 256 (stride 264)
    __shared__ __align__(16) u16 sH2[32 * 264];

    const u16* w0frag = wsFrag + F_EW0;
    const u16* w1frag = wsFrag + F_EW1;
    const u16* w2frag = wsFrag + F_EW2;

    const int tid  = threadIdx.x;
    const int blk  = blockIdx.x;
    const int b    = blk >> 6;
    const int i    = blk & 63;
    const int wave = tid >> 6;
    const int lane = tid & 63;
    const int quad = lane >> 4;
    const int mr   = lane & 15;
    const int mtile = wave & 1;
    const int nhalf = wave >> 1;

    for (int idx = tid; idx < 832; idx += 256) sXo[idx] = xo[(size_t)b * 832 + idx];
    sBias[tid]       = eb0[tid];
    sBias[256 + tid] = eb1[tid];
    __syncthreads();

    const float pix = sXo[i * 13 + 0], piy = sXo[i * 13 + 1], piz = sXo[i * 13 + 2];
    if (tid < 64) {
        float dx = pix - sXo[tid * 13 + 0];
        float dy = piy - sXo[tid * 13 + 1];
        float dz = piz - sXo[tid * 13 + 2];
        sAnorm[tid] = expf(-(dx * dx + dy * dy + dz * dz) * 11.111111111111111f);
    }
    __syncthreads();
    if (tid == 0) {
        float s = 0.0f;
        #pragma unroll
        for (int q = 0; q < 64; ++q) s += sAnorm[q];
        sInv = 1.0f / s;
    }
    __syncthreads();
    if (tid < 64) sAnorm[tid] *= sInv;
    const float tval = tp[0];

    float msum = (tid < 13) ? eb2[tid] : 0.0f;   // bias folded: sum(Anorm)=1

    for (int pass = 0; pass < 2; ++pass) {
        const int j0 = pass * 32;
        // ---- build In (32 edges x K=32, bf16) ----
        for (int idx = tid; idx < 1024; idx += 256) {
            int e = idx >> 5, k = idx & 31;
            int j = j0 + e;
            float v;
            if (k < 13) v = sXo[i * 13 + k];
            else if (k < 26) v = sXo[j * 13 + (k - 13)];
            else if (k < 29) { int c = k - 26; v = sXo[j * 13 + c] - sXo[i * 13 + c]; }
            else if (k == 29) {
                float dx = sXo[j * 13 + 0] - pix;
                float dy = sXo[j * 13 + 1] - piy;
                float dz = sXo[j * 13 + 2] - piz;
                v = sqrtf(dx * dx + dy * dy + dz * dz);
            } else if (k == 30) v = tval;
            else v = 0.0f;
            sIn[e * 40 + k] = f2bf(v);
        }
        __syncthreads();

        // ---- Layer 1: In[32x32] @ W0[32x256] ----
        {
            short8 afrag = *(const short8*)(sIn + (mtile * 16 + mr) * 40 + quad * 8);
            #pragma unroll
            for (int p = 0; p < 4; ++p) {
                int nt = nhalf * 8 + p * 2;
                float bv0 = sBias[nt * 16 + mr];
                float bv1 = sBias[nt * 16 + 16 + mr];
                f32x4 acc0 = { bv0, bv0, bv0, bv0 };
                f32x4 acc1 = { bv1, bv1, bv1, bv1 };
                short8 bf0 = *(const short8*)(w0frag + (nt * 64 + lane) * 8);
                short8 bf1 = *(const short8*)(w0frag + ((nt + 1) * 64 + lane) * 8);
                acc0 = __builtin_amdgcn_mfma_f32_16x16x32_bf16(afrag, bf0, acc0, 0, 0, 0);
                acc1 = __builtin_amdgcn_mfma_f32_16x16x32_bf16(afrag, bf1, acc1, 0, 0, 0);
                #pragma unroll
                for (int r = 0; r < 4; ++r) {
                    int row = mtile * 16 + quad * 4 + r;
                    sH1[row * 264 + nt * 16 + mr]       = f2bf(gelu_f(acc0[r]));
                    sH1[row * 264 + (nt + 1) * 16 + mr] = f2bf(gelu_f(acc1[r]));
                }
            }
        }
        __syncthreads();

        // ---- Layer 2: H1[32x256] @ W1[256x256] -> H2 ----
        #pragma unroll
        for (int p = 0; p < 4; ++p) {
            int nt = nhalf * 8 + p * 2;
            float bv0 = sBias[256 + nt * 16 + mr];
            float bv1 = sBias[256 + nt * 16 + 16 + mr];
            f32x4 acc0 = { bv0, bv0, bv0, bv0 };
            f32x4 acc1 = { bv1, bv1, bv1, bv1 };
            #pragma unroll
            for (int kt = 0; kt < 8; ++kt) {
                short8 a  = *(const short8*)(sH1 + (mtile * 16 + mr) * 264 + kt * 32 + quad * 8);
                short8 b0 = *(const short8*)(w1frag + ((kt * 16 + nt) * 64 + lane) * 8);
                short8 b1 = *(const short8*)(w1frag + ((kt * 16 + nt + 1) * 64 + lane) * 8);
                acc0 = __builtin_amdgcn_mfma_f32_16x16x32_bf16(a, b0, acc0, 0, 0, 0);
                acc1 = __builtin_amdgcn_mfma_f32_16x16x32_bf16(a, b1, acc1, 0, 0, 0);
            }
            #pragma unroll
            for (int r = 0; r < 4; ++r) {
                int row = mtile * 16 + quad * 4 + r;
                sH2[row * 264 + nt * 16 + mr]       = f2bf(gelu_f(acc0[r]));
                sH2[row * 264 + (nt + 1) * 16 + mr] = f2bf(gelu_f(acc1[r]));
            }
        }
        __syncthreads();

        // ---- Layer 3 (MFMA, N=16 padded): msg = H2 @ W2, scaled by Anorm ----
        if (nhalf == 0) {
            f32x4 acc = { 0.0f, 0.0f, 0.0f, 0.0f };
            #pragma unroll
            for (int kt = 0; kt < 8; ++kt) {
                short8 a = *(const short8*)(sH2 + (mtile * 16 + mr) * 264 + kt * 32 + quad * 8);
                short8 bf = *(const short8*)(w2frag + (kt * 64 + lane) * 8);
                acc = __builtin_amdgcn_mfma_f32_16x16x32_bf16(a, bf, acc, 0, 0, 0);
            }
            #pragma unroll
            for (int r = 0; r < 4; ++r) {
                int e = mtile * 16 + quad * 4 + r;
                sMsg[e * 16 + mr] = acc[r] * sAnorm[j0 + e];
            }
        }
        __syncthreads();

        if (tid < 13) {
            float s = 0.0f;
            #pragma unroll
            for (int e = 0; e < 32; ++e) s += sMsg[e * 16 + tid];
            msum += s;
        }
        __syncthreads();
    }

    if (tid < 13) mobj[blk * 16 + tid] = msum;
}

// K2: node MLPs via MFMA. 8 blocks: (ml 0/1) x (4 groups of 64 nodes).
__global__ __launch_bounds__(256) void k2_node(const float* __restrict__ xo,
                                               const float* __restrict__ tp,
                                               const float* __restrict__ mobj,
                                               const float* __restrict__ vb0,
                                               const float* __restrict__ vb1,
                                               const float* __restrict__ vb2,
                                               const float* __restrict__ vb3,
                                               const float* __restrict__ ob0,
                                               const float* __restrict__ ob1,
                                               const float* __restrict__ ob2,
                                               const float* __restrict__ ob3,
                                               const u16* __restrict__ wsFrag,
                                               float* __restrict__ out_dxo) {
    __shared__ __align__(16) u16 sIn[64 * 40];
    __shared__ __align__(16) u16 sHa[64 * 264];
    __shared__ __align__(16) u16 sHb[64 * 264];
    __shared__ float sBias[772];
    __shared__ float sOut3[256];

    const int tid  = threadIdx.x;
    const int bid  = blockIdx.x;
    const int ml   = bid >> 2;
    const int m0   = (bid & 3) * 64;
    const int wave = tid >> 6;
    const int lane = tid & 63;
    const int quad = lane >> 4;
    const int mr   = lane & 15;

    const u16* w0f = wsFrag + (ml ? F_OW0 : F_VW0);
    const u16* w1f = wsFrag + (ml ? F_OW1 : F_VW1);
    const u16* w2f = wsFrag + (ml ? F_OW2 : F_VW2);
    const u16* w3f = wsFrag + (ml ? F_OW3 : F_VW3);
    const float* b0 = ml ? ob0 : vb0;
    const float* b1 = ml ? ob1 : vb1;
    const float* b2 = ml ? ob2 : vb2;
    const float* b3 = ml ? ob3 : vb3;

    sBias[tid]       = b0[tid];
    sBias[256 + tid] = b1[tid];
    sBias[512 + tid] = b2[tid];
    if (tid < 3) sBias[768 + tid] = b3[tid];

    const float tval = tp[0];
    for (int idx = tid; idx < 64 * 32; idx += 256) {
        int m = idx >> 5, k = idx & 31;
        int n = m0 + m;
        float v;
        if (k < 13)      v = xo[n * 13 + k];
        else if (k < 26) v = mobj[n * 16 + (k - 13)];
        else if (k == 26) v = tval;
        else v = 0.0f;
        sIn[m * 40 + k] = f2bf(v);
    }
    __syncthreads();

    // Layer 1
    {
        short8 afrag = *(const short8*)(sIn + (wave * 16 + mr) * 40 + quad * 8);
        #pragma unroll
        for (int p = 0; p < 8; ++p) {
            int nt = p * 2;
            float bv0 = sBias[nt * 16 + mr];
            float bv1 = sBias[nt * 16 + 16 + mr];
            f32x4 acc0 = { bv0, bv0, bv0, bv0 };
            f32x4 acc1 = { bv1, bv1, bv1, bv1 };
            short8 bf0 = *(const short8*)(w0f + (nt * 64 + lane) * 8);
            short8 bf1 = *(const short8*)(w0f + ((nt + 1) * 64 + lane) * 8);
            acc0 = __builtin_amdgcn_mfma_f32_16x16x32_bf16(afrag, bf0, acc0, 0, 0, 0);
            acc1 = __builtin_amdgcn_mfma_f32_16x16x32_bf16(afrag, bf1, acc1, 0, 0, 0);
            #pragma unroll
            for (int r = 0; r < 4; ++r) {
                int row = wave * 16 + quad * 4 + r;
                sHa[row * 264 + nt * 16 + mr]       = f2bf(gelu_f(acc0[r]));
                sHa[row * 264 + (nt + 1) * 16 + mr] = f2bf(gelu_f(acc1[r]));
            }
        }
    }
    __syncthreads();

    // Layer 2
    #pragma unroll
    for (int p = 0; p < 8; ++p) {
        int nt = p * 2;
        float bv0 = sBias[256 + nt * 16 + mr];
        float bv1 = sBias[256 + nt * 16 + 16 + mr];
        f32x4 acc0 = { bv0, bv0, bv0, bv0 };
        f32x4 acc1 = { bv1, bv1, bv1, bv1 };
        #pragma unroll
        for (int kt = 0; kt < 8; ++kt) {
            short8 a  = *(const short8*)(sHa + (wave * 16 + mr) * 264 + kt * 32 + quad * 8);
            short8 bf0 = *(const short8*)(w1f + ((kt * 16 + nt) * 64 + lane) * 8);
            short8 bf1 = *(const short8*)(w1f + ((kt * 16 + nt + 1) * 64 + lane) * 8);
            acc0 = __builtin_amdgcn_mfma_f32_16x16x32_bf16(a, bf0, acc0, 0, 0, 0);
            acc1 = __builtin_amdgcn_mfma_f32_16x16x32_bf16(a, bf1, acc1, 0, 0, 0);
        }
        #pragma unroll
        for (int r = 0; r < 4; ++r) {
            int row = wave * 16 + quad * 4 + r;
            sHb[row * 264 + nt * 16 + mr]       = f2bf(gelu_f(acc0[r]));
            sHb[row * 264 + (nt + 1) * 16 + mr] = f2bf(gelu_f(acc1[r]));
        }
    }
    __syncthreads();

    // Layer 3
    #pragma unroll
    for (int p = 0; p < 8; ++p) {
        int nt = p * 2;
        float bv0 = sBias[512 + nt * 16 + mr];
        float bv1 = sBias[512 + nt * 16 + 16 + mr];
        f32x4 acc0 = { bv0, bv0, bv0, bv0 };
        f32x4 acc1 = { bv1, bv1, bv1, bv1 };
        #pragma unroll
        for (int kt = 0; kt < 8; ++kt) {
            short8 a  = *(const short8*)(sHb + (wave * 16 + mr) * 264 + kt * 32 + quad * 8);
            short8 bf0 = *(const short8*)(w2f + ((kt * 16 + nt) * 64 + lane) * 8);
            short8 bf1 = *(const short8*)(w2f + ((kt * 16 + nt + 1) * 64 + lane) * 8);
            acc0 = __builtin_amdgcn_mfma_f32_16x16x32_bf16(a, bf0, acc0, 0, 0, 0);
            acc1 = __builtin_amdgcn_mfma_f32_16x16x32_bf16(a, bf1, acc1, 0, 0, 0);
        }
        #pragma unroll
        for (int r = 0; r < 4; ++r) {
            int row = wave * 16 + quad * 4 + r;
            sHa[row * 264 + nt * 16 + mr]       = f2bf(gelu_f(acc0[r]));
            sHa[row * 264 + (nt + 1) * 16 + mr] = f2bf(gelu_f(acc1[r]));
        }
    }
    __syncthreads();

    // Layer 4: Ha @ W3[256x16(3)]
    {
        float bv = (mr < 3) ? sBias[768 + mr] : 0.0f;
        f32x4 acc = { bv, bv, bv, bv };
        #pragma unroll
        for (int kt = 0; kt < 8; ++kt) {
            short8 a  = *(const short8*)(sHa + (wave * 16 + mr) * 264 + kt * 32 + quad * 8);
            short8 bf = *(const short8*)(w3f + (kt * 64 + lane) * 8);
            acc = __builtin_amdgcn_mfma_f32_16x16x32_bf16(a, bf, acc, 0, 0, 0);
        }
        if (mr < 3) {
            #pragma unroll
            for (int r = 0; r < 4; ++r) {
                int row = wave * 16 + quad * 4 + r;
                sOut3[row * 4 + mr] = acc[r];
            }
        }
    }
    __syncthreads();

    if (tid < 64) {
        int n = m0 + tid;
        const float* xrow = xo + (size_t)n * CDO;
        float* o = out_dxo + (size_t)n * CDO;
        if (ml == 0) {
            o[0] = xrow[3]; o[1] = xrow[4]; o[2] = xrow[5];
            o[3] = sOut3[tid * 4 + 0];
            o[4] = sOut3[tid * 4 + 1];
            o[5] = sOut3[tid * 4 + 2];
        } else {
            float qw = xrow[6], qx = xrow[7], qy = xrow[8], qz = xrow[9];
            float ox = xrow[10], oy = xrow[11], oz = xrow[12];
            o[6] = -0.5f * (ox * qx + oy * qy + oz * qz);
            o[7] =  0.5f * (ox * qw + oy * qz - oz * qy);
            o[8] =  0.5f * (-ox * qz + oy * qw + oz * qx);
            o[9] =  0.5f * (ox * qy - oy * qx + oz * qw);
            o[10] = sOut3[tid * 4 + 0];
            o[11] = sOut3[tid * 4 + 1];
            o[12] = sOut3[tid * 4 + 2];
        }
    }
}

// K3: particle kernel; S staged through LDS in two 32-object half-tiles
// (stride-33 padding: staging 2 lanes/bank, compute (p+o)%32 2 lanes/bank — both free).
__global__ __launch_bounds__(256) void k3_part(const float* __restrict__ xp,
                                               const float* __restrict__ S,
                                               const float* __restrict__ xo,
                                               float* __restrict__ out) {
    __shared__ float sXo[832];
    __shared__ float sPar[768];
    __shared__ __align__(16) float sS[256 * 33];     // 33.8 KB
    __shared__ __align__(16) float sXp[3328];
    __shared__ __align__(16) float sOutF[3328];

    const int tid  = threadIdx.x;
    const int blk  = blockIdx.x;
    const int pid0 = blk << 8;
    const int b    = pid0 >> 15;

    for (int idx = tid; idx < 832; idx += 256) sXo[idx] = xo[(size_t)b * 832 + idx];
    {
        const float4* src = (const float4*)(xp) + (size_t)blk * 832;
        float4* dst = (float4*)sXp;
        for (int idx = tid; idx < 832; idx += 256) dst[idx] = src[idx];
    }
    __syncthreads();

    if (tid < 64) {
        const int r = tid * CDO;
        float cx = sXo[r + 0], cy = sXo[r + 1], cz = sXo[r + 2];
        float vx = sXo[r + 3], vy = sXo[r + 4], vz = sXo[r + 5];
        float qw = sXo[r + 6], qx = sXo[r + 7], qy = sXo[r + 8], qz = sXo[r + 9];
        float ox = sXo[r + 10], oy = sXo[r + 11], oz = sXo[r + 12];
        float s2 = qw * qw - (qx * qx + qy * qy + qz * qz);
        float R00 = s2 + 2.f*qx*qx,        R01 = 2.f*qx*qy - 2.f*qw*qz, R02 = 2.f*qx*qz + 2.f*qw*qy;
        float R10 = 2.f*qy*qx + 2.f*qw*qz, R11 = s2 + 2.f*qy*qy,        R12 = 2.f*qy*qz - 2.f*qw*qx;
        float R20 = 2.f*qz*qx - 2.f*qw*qy, R21 = 2.f*qz*qy + 2.f*qw*qx, R22 = s2 + 2.f*qz*qz;
        float W00 = -oz*R10 + oy*R20, W01 = -oz*R11 + oy*R21, W02 = -oz*R12 + oy*R22;
        float W10 =  oz*R00 - ox*R20, W11 =  oz*R01 - ox*R21, W12 =  oz*R02 - ox*R22;
        float W20 = -oy*R00 + ox*R10, W21 = -oy*R01 + ox*R11, W22 = -oy*R02 + ox*R12;
        float* par = sPar + tid * 12;
        par[0] = vx - (W00*cx + W01*cy + W02*cz);
        par[1] = vy - (W10*cx + W11*cy + W12*cz);
        par[2] = vz - (W20*cx + W21*cy + W22*cz);
        par[3] = W00; par[4]  = W01; par[5]  = W02;
        par[6] = W10; par[7]  = W11; par[8]  = W12;
        par[9] = W20; par[10] = W21; par[11] = W22;
    }

    float fvx = 0.0f, fvy = 0.0f, fvz = 0.0f;
    const int p13 = tid * CDO;

    #pragma unroll
    for (int half = 0; half < 2; ++half) {
        __syncthreads();
        // stage S[pid0+p][half*32 + o] -> sS[p*33 + o], coalesced float4 reads
        const float4* Sg = (const float4*)(S) + ((size_t)pid0 * 16) + half * 8;
        for (int idx = tid; idx < 2048; idx += 256) {
            int p = idx >> 3, o4 = idx & 7;
            float4 v = Sg[(size_t)p * 16 + o4];
            float* d = sS + p * 33 + o4 * 4;
            d[0] = v.x; d[1] = v.y; d[2] = v.z; d[3] = v.w;
        }
        __syncthreads();

        const float* pr   = sS + tid * 33;
        const float* parh = sPar + half * 32 * 12;
        #pragma unroll
        for (int o = 0; o < 32; ++o) {
            float s = pr[o];
            const float* pp = parh + o * 12;
            float px = sXp[p13 + 10], py = sXp[p13 + 11], pz = sXp[p13 + 12];
            float tx = pp[0] + pp[3] * px + pp[4]  * py + pp[5]  * pz;
            float ty = pp[1] + pp[6] * px + pp[7]  * py + pp[8]  * pz;
            float tz = pp[2] + pp[9] * px + pp[10] * py + pp[11] * pz;
            fvx = fmaf(s, tx, fvx);
            fvy = fmaf(s, ty, fvy);
            fvz = fmaf(s, tz, fvz);
        }
    }

    const float cvx = sXp[p13 + 3], cvy = sXp[p13 + 4], cvz = sXp[p13 + 5];
    sOutF[p13 + 0] = fvx;
    sOutF[p13 + 1] = fvy;
    sOutF[p13 + 2] = fvz;
    sOutF[p13 + 3] = fvx - cvx;
    sOutF[p13 + 4] = fvy - cvy;
    sOutF[p13 + 5] = fvz - cvz;
    #pragma unroll
    for (int q = 6; q < 13; ++q) sOutF[p13 + q] = 0.0f;
    __syncthreads();
    {
        float4* dstg = (float4*)(out) + (size_t)blk * 832;
        const float4* srcl = (const float4*)sOutF;
        for (int idx = tid; idx < 832; idx += 256) dstg[idx] = srcl[idx];
    }
}

extern "C" void kernel_launch(void* const* d_in, const int* in_sizes, int n_in,
                              void* d_out, int out_size, void* d_ws, size_t ws_size,
                              hipStream_t stream) {
    const float* t  = (const float*)d_in[0];
    const float* xp = (const float*)d_in[1];
    const float* xo = (const float*)d_in[2];
    const float* S  = (const float*)d_in[3];
    float* mobj = (float*)d_ws;
    u16* wsFrag = (u16*)((char*)d_ws + WSB_FRAG);
    float* out = (float*)d_out;

    Segs segs;
    segs.src[0]  = (const float*)d_in[4];   // ew0
    segs.src[1]  = (const float*)d_in[6];   // ew1
    segs.src[2]  = (const float*)d_in[8];   // ew2
    segs.src[3]  = (const float*)d_in[10];  // vw0
    segs.src[4]  = (const float*)d_in[12];  // vw1
    segs.src[5]  = (const float*)d_in[14];  // vw2
    segs.src[6]  = (const float*)d_in[16];  // vw3
    segs.src[7]  = (const float*)d_in[18];  // ow0
    segs.src[8]  = (const float*)d_in[20];  // ow1
    segs.src[9]  = (const float*)d_in[22];  // ow2
    segs.src[10] = (const float*)d_in[24];  // ow3

    hipLaunchKernelGGL(k0_prep, dim3(1440), dim3(256), 0, stream, segs, mobj, wsFrag);
    hipLaunchKernelGGL(k1_edge, dim3(256), dim3(256), 0, stream,
                       xo, t,
                       (const float*)d_in[5], (const float*)d_in[7], (const float*)d_in[9],
                       wsFrag, mobj);
    hipLaunchKernelGGL(k2_node, dim3(8), dim3(256), 0, stream,
                       xo, t, mobj,
                       (const float*)d_in[11], (const float*)d_in[13],
                       (const float*)d_in[15], (const float*)d_in[17],
                       (const float*)d_in[19], (const float*)d_in[21],
                       (const float*)d_in[23], (const float*)d_in[25],
                       wsFrag, out + DXP_ELEMS);
    hipLaunchKernelGGL(k3_part, dim3(512), dim3(256), 0, stream,
                       xp, S, xo, out);
}

// Round 8
// 190.182 us; speedup vs baseline: 1.0647x; 1.0647x over previous
//
#include <hip/hip_runtime.h>
#include <math.h>

typedef unsigned short u16;
typedef unsigned int   u32;

typedef __attribute__((ext_vector_type(8))) short short8;
typedef __attribute__((ext_vector_type(4))) float f32x4;

static constexpr int CB  = 4;
static constexpr int CNP = 32768;
static constexpr int CM  = 64;
static constexpr int CDO = 13;
static constexpr int CH  = 256;
static constexpr int DXP_ELEMS = CB * CNP * CDO;   // 1703936 floats; dx_o follows

// ws layout: [0,16384) bytes = mobj float[4096]; frag pool (bf16) at byte 16384.
static constexpr int WSB_FRAG = 16384;
// frag pool offsets (bf16 elems) — all multiples of 256
static constexpr int F_EW0 = 0;        // 8192   (31x256 -> K32)
static constexpr int F_EW1 = 8192;     // 65536  (256x256)
static constexpr int F_EW2 = 73728;    // 4096   (256x13 -> N16)
static constexpr int F_VW0 = 77824;    // 8192   (27x256 -> K32)
static constexpr int F_VW1 = 86016;    // 65536
static constexpr int F_VW2 = 151552;   // 65536
static constexpr int F_VW3 = 217088;   // 4096   (256x3 -> N16)
static constexpr int F_OW0 = 221184;
static constexpr int F_OW1 = 229376;
static constexpr int F_OW2 = 294912;
static constexpr int F_OW3 = 360448;
static constexpr int F_TOTAL = 364544;
static constexpr int K0_BLOCKS = F_TOTAL / 256;    // 1424
static constexpr int K3_BLOCKS = (CB * CNP) / 256; // 512

__device__ __forceinline__ float bf2f(u16 v) { return __uint_as_float(((u32)v) << 16); }
__device__ __forceinline__ u16 f2bf(float f) {
    u32 u = __float_as_uint(f);
    u += 0x7fffu + ((u >> 16) & 1u);
    return (u16)(u >> 16);
}
// fast tanh-gelu (max |err| vs exact erf-gelu ~1.5e-3, well inside 2% budget)
__device__ __forceinline__ float gelu_f(float x) {
    float y = 0.7978845608028654f * (x + 0.044715f * x * x * x);
    float e = __expf(2.0f * y);
    float t = 1.0f - 2.0f / (e + 1.0f);
    return 0.5f * x * (1.0f + t);
}

struct Segs { const float* src[11]; };

// K03: fused (independent) work:
//  blocks [0, K0_BLOCKS)          : swizzle MLP weights into MFMA B-frag order (bf16) in ws
//  blocks [K0_BLOCKS, +K3_BLOCKS) : particle kernel (dx_p)
// B-frag (16x16x32): frag[((kt*NT+nt)*64 + lane)*8 + j] = W[kt*32 + (lane>>4)*8 + j][nt*16 + (lane&15)]
__global__ __launch_bounds__(256) void k03_prep_part(Segs segs, u16* __restrict__ wsFrag,
                                                     const float* __restrict__ xp,
                                                     const float* __restrict__ S,
                                                     const float* __restrict__ xo,
                                                     float* __restrict__ out) {
    __shared__ float sXo[832];
    __shared__ float sPar[768];
    __shared__ __align__(16) float sXp[3328];
    __shared__ __align__(16) float sOutF[3328];

    const int tid = threadIdx.x;

    if (blockIdx.x < K0_BLOCKS) {
        // ---------------- weight swizzle ----------------
        int f = blockIdx.x * 256 + tid;
        const float* src; int base, K, N, NT;
        if      (f < F_EW1) { src = segs.src[0];  base = F_EW0; K = 31;  N = 256; NT = 16; }
        else if (f < F_EW2) { src = segs.src[1];  base = F_EW1; K = 256; N = 256; NT = 16; }
        else if (f < F_VW0) { src = segs.src[2];  base = F_EW2; K = 256; N = 13;  NT = 1;  }
        else if (f < F_VW1) { src = segs.src[3];  base = F_VW0; K = 27;  N = 256; NT = 16; }
        else if (f < F_VW2) { src = segs.src[4];  base = F_VW1; K = 256; N = 256; NT = 16; }
        else if (f < F_VW3) { src = segs.src[5];  base = F_VW2; K = 256; N = 256; NT = 16; }
        else if (f < F_OW0) { src = segs.src[6];  base = F_VW3; K = 256; N = 3;   NT = 1;  }
        else if (f < F_OW1) { src = segs.src[7];  base = F_OW0; K = 27;  N = 256; NT = 16; }
        else if (f < F_OW2) { src = segs.src[8];  base = F_OW1; K = 256; N = 256; NT = 16; }
        else if (f < F_OW3) { src = segs.src[9];  base = F_OW2; K = 256; N = 256; NT = 16; }
        else                { src = segs.src[10]; base = F_OW3; K = 256; N = 3;   NT = 1;  }
        int rel = f - base;
        int j = rel & 7, lane = (rel >> 3) & 63, t = rel >> 9;
        int nt = (NT == 16) ? (t & 15) : 0;
        int kt = (NT == 16) ? (t >> 4) : t;
        int k = kt * 32 + ((lane >> 4) << 3) + j;
        int n = nt * 16 + (lane & 15);
        float v = (k < K && n < N) ? src[k * N + n] : 0.0f;
        wsFrag[f] = f2bf(v);
        return;
    }

    // ---------------- particle kernel ----------------
    const int blk  = blockIdx.x - K0_BLOCKS;
    const int pid0 = blk << 8;
    const int b    = pid0 >> 15;

    for (int idx = tid; idx < 832; idx += 256) sXo[idx] = xo[(size_t)b * 832 + idx];
    {
        const float4* src = (const float4*)(xp) + (size_t)blk * 832;
        float4* dst = (float4*)sXp;
        for (int idx = tid; idx < 832; idx += 256) dst[idx] = src[idx];
    }
    __syncthreads();

    if (tid < 64) {
        const int r = tid * CDO;
        float cx = sXo[r + 0], cy = sXo[r + 1], cz = sXo[r + 2];
        float vx = sXo[r + 3], vy = sXo[r + 4], vz = sXo[r + 5];
        float qw = sXo[r + 6], qx = sXo[r + 7], qy = sXo[r + 8], qz = sXo[r + 9];
        float ox = sXo[r + 10], oy = sXo[r + 11], oz = sXo[r + 12];
        float s2 = qw * qw - (qx * qx + qy * qy + qz * qz);
        float R00 = s2 + 2.f*qx*qx,        R01 = 2.f*qx*qy - 2.f*qw*qz, R02 = 2.f*qx*qz + 2.f*qw*qy;
        float R10 = 2.f*qy*qx + 2.f*qw*qz, R11 = s2 + 2.f*qy*qy,        R12 = 2.f*qy*qz - 2.f*qw*qx;
        float R20 = 2.f*qz*qx - 2.f*qw*qy, R21 = 2.f*qz*qy + 2.f*qw*qx, R22 = s2 + 2.f*qz*qz;
        float W00 = -oz*R10 + oy*R20, W01 = -oz*R11 + oy*R21, W02 = -oz*R12 + oy*R22;
        float W10 =  oz*R00 - ox*R20, W11 =  oz*R01 - ox*R21, W12 =  oz*R02 - ox*R22;
        float W20 = -oy*R00 + ox*R10, W21 = -oy*R01 + ox*R11, W22 = -oy*R02 + ox*R12;
        float* par = sPar + tid * 12;
        par[0] = vx - (W00*cx + W01*cy + W02*cz);
        par[1] = vy - (W10*cx + W11*cy + W12*cz);
        par[2] = vz - (W20*cx + W21*cy + W22*cz);
        par[3] = W00; par[4]  = W01; par[5]  = W02;
        par[6] = W10; par[7]  = W11; par[8]  = W12;
        par[9] = W20; par[10] = W21; par[11] = W22;
    }
    __syncthreads();

    const int p13 = tid * CDO;
    const float cvx = sXp[p13 + 3],  cvy = sXp[p13 + 4],  cvz = sXp[p13 + 5];
    const float px  = sXp[p13 + 10], py  = sXp[p13 + 11], pz  = sXp[p13 + 12];

    float fvx = 0.0f, fvy = 0.0f, fvz = 0.0f;
    const size_t pid = (size_t)pid0 + tid;
    const float4* srow = (const float4*)(S) + pid * 16;
    #pragma unroll
    for (int g = 0; g < 16; ++g) {
        float4 sv = srow[g];
        float sf[4] = { sv.x, sv.y, sv.z, sv.w };
        #pragma unroll
        for (int h = 0; h < 4; ++h) {
            float s = sf[h];
            const float* pp = sPar + (g * 4 + h) * 12;
            float tx = pp[0] + pp[3] * px + pp[4]  * py + pp[5]  * pz;
            float ty = pp[1] + pp[6] * px + pp[7]  * py + pp[8]  * pz;
            float tz = pp[2] + pp[9] * px + pp[10] * py + pp[11] * pz;
            fvx = fmaf(s, tx, fvx);
            fvy = fmaf(s, ty, fvy);
            fvz = fmaf(s, tz, fvz);
        }
    }

    sOutF[p13 + 0] = fvx;
    sOutF[p13 + 1] = fvy;
    sOutF[p13 + 2] = fvz;
    sOutF[p13 + 3] = fvx - cvx;
    sOutF[p13 + 4] = fvy - cvy;
    sOutF[p13 + 5] = fvz - cvz;
    #pragma unroll
    for (int q = 6; q < 13; ++q) sOutF[p13 + q] = 0.0f;
    __syncthreads();
    {
        float4* dstg = (float4*)(out) + (size_t)blk * 832;
        const float4* srcl = (const float4*)sOutF;
        for (int idx = tid; idx < 832; idx += 256) dstg[idx] = srcl[idx];
    }
}

// K1: fused edge MLP via MFMA. One block per (b,i): all 64 edges j, two passes of 32.
__global__ __launch_bounds__(256) void k1_edge(const float* __restrict__ xo,
                                               const float* __restrict__ tp,
                                               const float* __restrict__ eb0,
                                               const float* __restrict__ eb1,
                                               const float* __restrict__ eb2,
                                               const u16* __restrict__ wsFrag,
                                               float* __restrict__ mobj) {
    __shared__ float sXo[832];
    __shared__ float sAnorm[64];
    __shared__ float sInv;
    __shared__ float sBias[512];           // [0,256)=b0, [256,512)=b1
    __shared__ float sMsg[512];            // 32 edges x 16
    __shared__ __align__(16) u16 sIn[32 * 40];     // 32 edges x K32 (stride 40)
    __shared__ __align__(16) u16 sH1[32 * 264];    // 32 edges x 256 (stride 264)
    __shared__ __align__(16) u16 sH2[32 * 264];

    const u16* w0frag = wsFrag + F_EW0;
    const u16* w1frag = wsFrag + F_EW1;
    const u16* w2frag = wsFrag + F_EW2;

    const int tid  = threadIdx.x;
    const int blk  = blockIdx.x;
    const int b    = blk >> 6;
    const int i    = blk & 63;
    const int wave = tid >> 6;
    const int lane = tid & 63;
    const int quad = lane >> 4;
    const int mr   = lane & 15;
    const int mtile = wave & 1;
    const int nhalf = wave >> 1;

    for (int idx = tid; idx < 832; idx += 256) sXo[idx] = xo[(size_t)b * 832 + idx];
    sBias[tid]       = eb0[tid];
    sBias[256 + tid] = eb1[tid];
    __syncthreads();

    const float pix = sXo[i * 13 + 0], piy = sXo[i * 13 + 1], piz = sXo[i * 13 + 2];
    if (tid < 64) {
        float dx = pix - sXo[tid * 13 + 0];
        float dy = piy - sXo[tid * 13 + 1];
        float dz = piz - sXo[tid * 13 + 2];
        sAnorm[tid] = expf(-(dx * dx + dy * dy + dz * dz) * 11.111111111111111f);
    }
    __syncthreads();
    if (tid == 0) {
        float s = 0.0f;
        #pragma unroll
        for (int q = 0; q < 64; ++q) s += sAnorm[q];
        sInv = 1.0f / s;
    }
    __syncthreads();
    if (tid < 64) sAnorm[tid] *= sInv;
    const float tval = tp[0];

    float msum = (tid < 13) ? eb2[tid] : 0.0f;   // bias folded: sum(Anorm)=1

    for (int pass = 0; pass < 2; ++pass) {
        const int j0 = pass * 32;
        // ---- build In (32 edges x K=32, bf16) ----
        for (int idx = tid; idx < 1024; idx += 256) {
            int e = idx >> 5, k = idx & 31;
            int j = j0 + e;
            float v;
            if (k < 13) v = sXo[i * 13 + k];
            else if (k < 26) v = sXo[j * 13 + (k - 13)];
            else if (k < 29) { int c = k - 26; v = sXo[j * 13 + c] - sXo[i * 13 + c]; }
            else if (k == 29) {
                float dx = sXo[j * 13 + 0] - pix;
                float dy = sXo[j * 13 + 1] - piy;
                float dz = sXo[j * 13 + 2] - piz;
                v = sqrtf(dx * dx + dy * dy + dz * dz);
            } else if (k == 30) v = tval;
            else v = 0.0f;
            sIn[e * 40 + k] = f2bf(v);
        }
        __syncthreads();

        // ---- Layer 1: In[32x32] @ W0[32x256] ----
        {
            short8 afrag = *(const short8*)(sIn + (mtile * 16 + mr) * 40 + quad * 8);
            #pragma unroll
            for (int p = 0; p < 4; ++p) {
                int nt = nhalf * 8 + p * 2;
                float bv0 = sBias[nt * 16 + mr];
                float bv1 = sBias[nt * 16 + 16 + mr];
                f32x4 acc0 = { bv0, bv0, bv0, bv0 };
                f32x4 acc1 = { bv1, bv1, bv1, bv1 };
                short8 bf0 = *(const short8*)(w0frag + (nt * 64 + lane) * 8);
                short8 bf1 = *(const short8*)(w0frag + ((nt + 1) * 64 + lane) * 8);
                acc0 = __builtin_amdgcn_mfma_f32_16x16x32_bf16(afrag, bf0, acc0, 0, 0, 0);
                acc1 = __builtin_amdgcn_mfma_f32_16x16x32_bf16(afrag, bf1, acc1, 0, 0, 0);
                #pragma unroll
                for (int r = 0; r < 4; ++r) {
                    int row = mtile * 16 + quad * 4 + r;
                    sH1[row * 264 + nt * 16 + mr]       = f2bf(gelu_f(acc0[r]));
                    sH1[row * 264 + (nt + 1) * 16 + mr] = f2bf(gelu_f(acc1[r]));
                }
            }
        }
        __syncthreads();

        // ---- Layer 2: H1[32x256] @ W1[256x256] -> H2 ----
        #pragma unroll
        for (int p = 0; p < 4; ++p) {
            int nt = nhalf * 8 + p * 2;
            float bv0 = sBias[256 + nt * 16 + mr];
            float bv1 = sBias[256 + nt * 16 + 16 + mr];
            f32x4 acc0 = { bv0, bv0, bv0, bv0 };
            f32x4 acc1 = { bv1, bv1, bv1, bv1 };
            #pragma unroll
            for (int kt = 0; kt < 8; ++kt) {
                short8 a  = *(const short8*)(sH1 + (mtile * 16 + mr) * 264 + kt * 32 + quad * 8);
                short8 b0 = *(const short8*)(w1frag + ((kt * 16 + nt) * 64 + lane) * 8);
                short8 b1 = *(const short8*)(w1frag + ((kt * 16 + nt + 1) * 64 + lane) * 8);
                acc0 = __builtin_amdgcn_mfma_f32_16x16x32_bf16(a, b0, acc0, 0, 0, 0);
                acc1 = __builtin_amdgcn_mfma_f32_16x16x32_bf16(a, b1, acc1, 0, 0, 0);
            }
            #pragma unroll
            for (int r = 0; r < 4; ++r) {
                int row = mtile * 16 + quad * 4 + r;
                sH2[row * 264 + nt * 16 + mr]       = f2bf(gelu_f(acc0[r]));
                sH2[row * 264 + (nt + 1) * 16 + mr] = f2bf(gelu_f(acc1[r]));
            }
        }
        __syncthreads();

        // ---- Layer 3 (MFMA, N=16 padded): msg = H2 @ W2, scaled by Anorm ----
        if (nhalf == 0) {
            f32x4 acc = { 0.0f, 0.0f, 0.0f, 0.0f };
            #pragma unroll
            for (int kt = 0; kt < 8; ++kt) {
                short8 a = *(const short8*)(sH2 + (mtile * 16 + mr) * 264 + kt * 32 + quad * 8);
                short8 bf = *(const short8*)(w2frag + (kt * 64 + lane) * 8);
                acc = __builtin_amdgcn_mfma_f32_16x16x32_bf16(a, bf, acc, 0, 0, 0);
            }
            #pragma unroll
            for (int r = 0; r < 4; ++r) {
                int e = mtile * 16 + quad * 4 + r;
                sMsg[e * 16 + mr] = acc[r] * sAnorm[j0 + e];
            }
        }
        __syncthreads();

        if (tid < 13) {
            float s = 0.0f;
            #pragma unroll
            for (int e = 0; e < 32; ++e) s += sMsg[e * 16 + tid];
            msum += s;
        }
        __syncthreads();
    }

    if (tid < 13) mobj[blk * 16 + tid] = msum;
}

// K2: node MLPs via MFMA. 8 blocks: (ml 0/1) x (4 groups of 64 nodes).
__global__ __launch_bounds__(256) void k2_node(const float* __restrict__ xo,
                                               const float* __restrict__ tp,
                                               const float* __restrict__ mobj,
                                               const float* __restrict__ vb0,
                                               const float* __restrict__ vb1,
                                               const float* __restrict__ vb2,
                                               const float* __restrict__ vb3,
                                               const float* __restrict__ ob0,
                                               const float* __restrict__ ob1,
                                               const float* __restrict__ ob2,
                                               const float* __restrict__ ob3,
                                               const u16* __restrict__ wsFrag,
                                               float* __restrict__ out_dxo) {
    __shared__ __align__(16) u16 sIn[64 * 40];
    __shared__ __align__(16) u16 sHa[64 * 264];
    __shared__ __align__(16) u16 sHb[64 * 264];
    __shared__ float sBias[772];
    __shared__ float sOut3[256];

    const int tid  = threadIdx.x;
    const int bid  = blockIdx.x;
    const int ml   = bid >> 2;
    const int m0   = (bid & 3) * 64;
    const int wave = tid >> 6;
    const int lane = tid & 63;
    const int quad = lane >> 4;
    const int mr   = lane & 15;

    const u16* w0f = wsFrag + (ml ? F_OW0 : F_VW0);
    const u16* w1f = wsFrag + (ml ? F_OW1 : F_VW1);
    const u16* w2f = wsFrag + (ml ? F_OW2 : F_VW2);
    const u16* w3f = wsFrag + (ml ? F_OW3 : F_VW3);
    const float* b0 = ml ? ob0 : vb0;
    const float* b1 = ml ? ob1 : vb1;
    const float* b2 = ml ? ob2 : vb2;
    const float* b3 = ml ? ob3 : vb3;

    sBias[tid]       = b0[tid];
    sBias[256 + tid] = b1[tid];
    sBias[512 + tid] = b2[tid];
    if (tid < 3) sBias[768 + tid] = b3[tid];

    const float tval = tp[0];
    for (int idx = tid; idx < 64 * 32; idx += 256) {
        int m = idx >> 5, k = idx & 31;
        int n = m0 + m;
        float v;
        if (k < 13)      v = xo[n * 13 + k];
        else if (k < 26) v = mobj[n * 16 + (k - 13)];
        else if (k == 26) v = tval;
        else v = 0.0f;
        sIn[m * 40 + k] = f2bf(v);
    }
    __syncthreads();

    // Layer 1
    {
        short8 afrag = *(const short8*)(sIn + (wave * 16 + mr) * 40 + quad * 8);
        #pragma unroll
        for (int p = 0; p < 8; ++p) {
            int nt = p * 2;
            float bv0 = sBias[nt * 16 + mr];
            float bv1 = sBias[nt * 16 + 16 + mr];
            f32x4 acc0 = { bv0, bv0, bv0, bv0 };
            f32x4 acc1 = { bv1, bv1, bv1, bv1 };
            short8 bf0 = *(const short8*)(w0f + (nt * 64 + lane) * 8);
            short8 bf1 = *(const short8*)(w0f + ((nt + 1) * 64 + lane) * 8);
            acc0 = __builtin_amdgcn_mfma_f32_16x16x32_bf16(afrag, bf0, acc0, 0, 0, 0);
            acc1 = __builtin_amdgcn_mfma_f32_16x16x32_bf16(afrag, bf1, acc1, 0, 0, 0);
            #pragma unroll
            for (int r = 0; r < 4; ++r) {
                int row = wave * 16 + quad * 4 + r;
                sHa[row * 264 + nt * 16 + mr]       = f2bf(gelu_f(acc0[r]));
                sHa[row * 264 + (nt + 1) * 16 + mr] = f2bf(gelu_f(acc1[r]));
            }
        }
    }
    __syncthreads();

    // Layer 2
    #pragma unroll
    for (int p = 0; p < 8; ++p) {
        int nt = p * 2;
        float bv0 = sBias[256 + nt * 16 + mr];
        float bv1 = sBias[256 + nt * 16 + 16 + mr];
        f32x4 acc0 = { bv0, bv0, bv0, bv0 };
        f32x4 acc1 = { bv1, bv1, bv1, bv1 };
        #pragma unroll
        for (int kt = 0; kt < 8; ++kt) {
            short8 a  = *(const short8*)(sHa + (wave * 16 + mr) * 264 + kt * 32 + quad * 8);
            short8 bf0 = *(const short8*)(w1f + ((kt * 16 + nt) * 64 + lane) * 8);
            short8 bf1 = *(const short8*)(w1f + ((kt * 16 + nt + 1) * 64 + lane) * 8);
            acc0 = __builtin_amdgcn_mfma_f32_16x16x32_bf16(a, bf0, acc0, 0, 0, 0);
            acc1 = __builtin_amdgcn_mfma_f32_16x16x32_bf16(a, bf1, acc1, 0, 0, 0);
        }
        #pragma unroll
        for (int r = 0; r < 4; ++r) {
            int row = wave * 16 + quad * 4 + r;
            sHb[row * 264 + nt * 16 + mr]       = f2bf(gelu_f(acc0[r]));
            sHb[row * 264 + (nt + 1) * 16 + mr] = f2bf(gelu_f(acc1[r]));
        }
    }
    __syncthreads();

    // Layer 3
    #pragma unroll
    for (int p = 0; p < 8; ++p) {
        int nt = p * 2;
        float bv0 = sBias[512 + nt * 16 + mr];
        float bv1 = sBias[512 + nt * 16 + 16 + mr];
        f32x4 acc0 = { bv0, bv0, bv0, bv0 };
        f32x4 acc1 = { bv1, bv1, bv1, bv1 };
        #pragma unroll
        for (int kt = 0; kt < 8; ++kt) {
            short8 a  = *(const short8*)(sHb + (wave * 16 + mr) * 264 + kt * 32 + quad * 8);
            short8 bf0 = *(const short8*)(w2f + ((kt * 16 + nt) * 64 + lane) * 8);
            short8 bf1 = *(const short8*)(w2f + ((kt * 16 + nt + 1) * 64 + lane) * 8);
            acc0 = __builtin_amdgcn_mfma_f32_16x16x32_bf16(a, bf0, acc0, 0, 0, 0);
            acc1 = __builtin_amdgcn_mfma_f32_16x16x32_bf16(a, bf1, acc1, 0, 0, 0);
        }
        #pragma unroll
        for (int r = 0; r < 4; ++r) {
            int row = wave * 16 + quad * 4 + r;
            sHa[row * 264 + nt * 16 + mr]       = f2bf(gelu_f(acc0[r]));
            sHa[row * 264 + (nt + 1) * 16 + mr] = f2bf(gelu_f(acc1[r]));
        }
    }
    __syncthreads();

    // Layer 4: Ha @ W3[256x16(3)]
    {
        float bv = (mr < 3) ? sBias[768 + mr] : 0.0f;
        f32x4 acc = { bv, bv, bv, bv };
        #pragma unroll
        for (int kt = 0; kt < 8; ++kt) {
            short8 a  = *(const short8*)(sHa + (wave * 16 + mr) * 264 + kt * 32 + quad * 8);
            short8 bf = *(const short8*)(w3f + (kt * 64 + lane) * 8);
            acc = __builtin_amdgcn_mfma_f32_16x16x32_bf16(a, bf, acc, 0, 0, 0);
        }
        if (mr < 3) {
            #pragma unroll
            for (int r = 0; r < 4; ++r) {
                int row = wave * 16 + quad * 4 + r;
                sOut3[row * 4 + mr] = acc[r];
            }
        }
    }
    __syncthreads();

    if (tid < 64) {
        int n = m0 + tid;
        const float* xrow = xo + (size_t)n * CDO;
        float* o = out_dxo + (size_t)n * CDO;
        if (ml == 0) {
            o[0] = xrow[3]; o[1] = xrow[4]; o[2] = xrow[5];
            o[3] = sOut3[tid * 4 + 0];
            o[4] = sOut3[tid * 4 + 1];
            o[5] = sOut3[tid * 4 + 2];
        } else {
            float qw = xrow[6], qx = xrow[7], qy = xrow[8], qz = xrow[9];
            float ox = xrow[10], oy = xrow[11], oz = xrow[12];
            o[6] = -0.5f * (ox * qx + oy * qy + oz * qz);
            o[7] =  0.5f * (ox * qw + oy * qz - oz * qy);
            o[8] =  0.5f * (-ox * qz + oy * qw + oz * qx);
            o[9] =  0.5f * (ox * qy - oy * qx + oz * qw);
            o[10] = sOut3[tid * 4 + 0];
            o[11] = sOut3[tid * 4 + 1];
            o[12] = sOut3[tid * 4 + 2];
        }
    }
}

extern "C" void kernel_launch(void* const* d_in, const int* in_sizes, int n_in,
                              void* d_out, int out_size, void* d_ws, size_t ws_size,
                              hipStream_t stream) {
    const float* t  = (const float*)d_in[0];
    const float* xp = (const float*)d_in[1];
    const float* xo = (const float*)d_in[2];
    const float* S  = (const float*)d_in[3];
    float* mobj = (float*)d_ws;
    u16* wsFrag = (u16*)((char*)d_ws + WSB_FRAG);
    float* out = (float*)d_out;

    Segs segs;
    segs.src[0]  = (const float*)d_in[4];   // ew0
    segs.src[1]  = (const float*)d_in[6];   // ew1
    segs.src[2]  = (const float*)d_in[8];   // ew2
    segs.src[3]  = (const float*)d_in[10];  // vw0
    segs.src[4]  = (const float*)d_in[12];  // vw1
    segs.src[5]  = (const float*)d_in[14];  // vw2
    segs.src[6]  = (const float*)d_in[16];  // vw3
    segs.src[7]  = (const float*)d_in[18];  // ow0
    segs.src[8]  = (const float*)d_in[20];  // ow1
    segs.src[9]  = (const float*)d_in[22];  // ow2
    segs.src[10] = (const float*)d_in[24];  // ow3

    hipLaunchKernelGGL(k03_prep_part, dim3(K0_BLOCKS + K3_BLOCKS), dim3(256), 0, stream,
                       segs, wsFrag, xp, S, xo, out);
    hipLaunchKernelGGL(k1_edge, dim3(256), dim3(256), 0, stream,
                       xo, t,
                       (const float*)d_in[5], (const float*)d_in[7], (const float*)d_in[9],
                       wsFrag, mobj);
    hipLaunchKernelGGL(k2_node, dim3(8), dim3(256), 0, stream,
                       xo, t, mobj,
                       (const float*)d_in[11], (const float*)d_in[13],
                       (const float*)d_in[15], (const float*)d_in[17],
                       (const float*)d_in[19], (const float*)d_in[21],
                       (const float*)d_in[23], (const float*)d_in[25],
                       wsFrag, out + DXP_ELEMS);
}